// Round 4
// baseline (78.738 us; speedup 1.0000x reference)
//
#include <hip/hip_runtime.h>
#include <math.h>

#define BB 32
#define NN 16384
#define SS 64
#define NSEG 512        // segments of 32 n
#define NCHUNK 16       // chunks of 1024 n per batch

__device__ __forceinline__ float wrapf(float d) {
    const float TWO_PI = 6.28318530717958648f;
    const float INV_TWO_PI = 0.15915494309189534f;
    const float PI = 3.14159274f;   // nearest-float pi
    float r = d - TWO_PI * rintf(d * INV_TWO_PI);
    if (r <= -PI) r += TWO_PI;
    else if (r > PI) r -= TWO_PI;
    return r;                        // (-pi, pi]
}

__device__ __forceinline__ unsigned int encf(float f) {
    unsigned int u = __float_as_uint(f);
    return (u & 0x80000000u) ? ~u : (u | 0x80000000u);   // order-preserving
}
__device__ __forceinline__ float decf(unsigned int u) {
    unsigned int b = (u & 0x80000000u) ? (u ^ 0x80000000u) : ~u;
    return __uint_as_float(b);
}

// kA: block g owns n-range [g*32, g*32+32) for ALL batches.
//  - reduce tgt b=0 plane rows -> tv/pc (LDS) + mask_g (global, written once)
//  - per-n: phase (f32, stored), phase_diff via cross products,
//    accumulate global mxy/mz/pdm (f64 atomics)
//  - per-(b,segment) wrapped-diff sums -> segsum
//  - posAx min/max via encoded atomicMax
__global__ __launch_bounds__(256) void kA(
    const float* __restrict__ z, const float* __restrict__ xr,
    const float* __restrict__ xi, const float* __restrict__ x,
    const float* __restrict__ tgt,
    float* __restrict__ phase_g, unsigned long long* __restrict__ mask_g,
    double* __restrict__ segsum, double* __restrict__ acc,
    unsigned int* __restrict__ ctrl)
{
    __shared__ float tv_s[32];
    __shared__ int   pc_s[32];
    __shared__ double red[12];

    const int g = blockIdx.x;
    const int t = threadIdx.x;
    const int lane = t & 63, wv = t >> 6;

    // ---- tgt segment reduction: 32 rows x 64 slices, 8 threads/row ----
    {
        const int r  = t >> 3;        // 0..31
        const int q8 = t & 7;
        const float4* tg4 = (const float4*)tgt + (size_t)(g * 32 + r) * 16 + q8 * 2;
        float4 v0 = tg4[0], v1 = tg4[1];
        float sum = v0.x + v0.y + v0.z + v0.w + v1.x + v1.y + v1.z + v1.w;
        unsigned int b8 =
            (v0.x > 0.001f ? 1u : 0u)  | (v0.y > 0.001f ? 2u : 0u)  |
            (v0.z > 0.001f ? 4u : 0u)  | (v0.w > 0.001f ? 8u : 0u)  |
            (v1.x > 0.001f ? 16u : 0u) | (v1.y > 0.001f ? 32u : 0u) |
            (v1.z > 0.001f ? 64u : 0u) | (v1.w > 0.001f ? 128u : 0u);
        unsigned long long bits = (unsigned long long)b8 << (q8 * 8);
        #pragma unroll
        for (int off = 1; off < 8; off <<= 1) {
            sum  += __shfl_xor(sum, off);
            bits |= __shfl_xor(bits, off);
        }
        if (q8 == 0) {
            tv_s[r] = sum;
            pc_s[r] = __popcll(bits);
            mask_g[g * 32 + r] = bits;
        }
    }
    __syncthreads();

    // ---- main per-n math: lane = b_local*8 + q, thread owns 4 n ----
    const int b = (wv << 3) + (lane >> 3);
    const int q = lane & 7;
    const int n = g * 32 + q * 4;
    const size_t base = (size_t)b * NN + n;

    const float4 zv  = *(const float4*)(z  + base);
    const float4 xrv = *(const float4*)(xr + base);
    const float4 xiv = *(const float4*)(xi + base);
    const float4 x4  = *(const float4*)(x + n);

    // posAx min/max (wave 0 covers all 32 values of this segment)
    if (wv == 0) {
        float mx4 = fmaxf(fmaxf(x4.x, x4.y), fmaxf(x4.z, x4.w));
        float mn4 = fminf(fminf(x4.x, x4.y), fminf(x4.z, x4.w));
        #pragma unroll
        for (int off = 32; off; off >>= 1) {
            mx4 = fmaxf(mx4, __shfl_down(mx4, off));
            mn4 = fminf(mn4, __shfl_down(mn4, off));
        }
        if (lane == 0) {
            atomicMax(&ctrl[0], encf(mx4));
            atomicMax(&ctrl[1], encf(-mn4));
        }
    }

    // halos at n-1 and n+4 via shfl (q-interior) or guarded loads (q edges)
    float xrp = __shfl_up(xrv.w, 1), xip = __shfl_up(xiv.w, 1), xpp = __shfl_up(x4.w, 1);
    float xrn = __shfl_down(xrv.x, 1), xin = __shfl_down(xiv.x, 1), xnn = __shfl_down(x4.x, 1);
    if (q == 0) {
        if (n > 0) { xrp = xr[base - 1]; xip = xi[base - 1]; xpp = x[n - 1]; }
        else       { xrp = 1.f; xip = 0.f; xpp = 0.f; }
    }
    if (q == 7) {
        if (n + 4 < NN) { xrn = xr[base + 4]; xin = xi[base + 4]; xnn = x[n + 4]; }
        else            { xrn = 1.f; xin = 0.f; xnn = 0.f; }
    }

    float xre[6] = {xrp, xrv.x, xrv.y, xrv.z, xrv.w, xrn};
    float xim[6] = {xip, xiv.x, xiv.y, xiv.z, xiv.w, xin};
    float xs[6]  = {xpp, x4.x, x4.y, x4.z, x4.w, xnn};

    float ur[6], ui[6], rad[6];
    #pragma unroll
    for (int j = 0; j < 6; ++j) {
        float rv = sqrtf(xre[j] * xre[j] + xim[j] * xim[j]);
        rad[j] = rv;
        float inv = rv > 0.f ? 1.0f / rv : 0.f;
        ur[j] = xre[j] * inv; ui[j] = xim[j] * inv;
    }
    const float zz[4] = {zv.x, zv.y, zv.z, zv.w};

    float4 ph4;
    float* php = (float*)&ph4;
    #pragma unroll
    for (int j = 0; j < 4; ++j) php[j] = atan2f(xim[j + 1], xre[j + 1]);

    float phprev = __shfl_up(php[3], 1);
    if (q == 0) phprev = atan2f(xip, xrp);   // phase at n-1 (unused for n==0)

    double a_mxy = 0.0, a_mz = 0.0, a_pdm = 0.0, a_ds = 0.0;
    #pragma unroll
    for (int j = 0; j < 4; ++j) {
        const int gn = n + j;
        const float tv = tv_s[q * 4 + j];
        const int   pc = pc_s[q * 4 + j];

        float d;
        if (j == 0) d = (gn == 0) ? php[0] : wrapf(php[0] - phprev);
        else        d = wrapf(php[j] - php[j - 1]);
        a_ds += (double)d;

        float dxl = xs[j + 1] - xs[j];
        float dxr = xs[j + 2] - xs[j + 1];
        float sinL = ui[j]     * ur[j + 1] - ur[j]     * ui[j + 1];
        float sinR = ui[j + 2] * ur[j + 1] - ur[j + 2] * ui[j + 1];
        float w, pd;
        if (gn == 0)           { w = 0.5f * dxr; pd =  sinR / dxr; }
        else if (gn == NN - 1) { w = 0.5f * dxl; pd = -sinL / dxl; }
        else {
            w = 0.5f * (dxl + dxr);
            float hs = dxl + dxr;
            float ca = -dxr / (dxl * hs);
            float cc =  dxl / (dxr * hs);
            pd = ca * sinL + cc * sinR;
        }
        float dmx = rad[j + 1] - tv;
        a_mxy += (double)(dmx * dmx) * (double)w;
        float tz = sqrtf(1.0f - tv * tv);
        float dz = zz[j] - tz;
        a_mz  += (double)(dz * dz) * (double)w;
        a_pdm += (double)(pd * pd) * (double)pc * (double)w;
    }
    *(float4*)(phase_g + base) = ph4;

    // per-(b,segment) diff sum: reduce over the 8-lane q-group
    #pragma unroll
    for (int off = 1; off < 8; off <<= 1) a_ds += __shfl_xor(a_ds, off);
    if (q == 0) segsum[(size_t)b * NSEG + g] = a_ds;

    // block-wide reduce of mxy/mz/pdm -> 3 global f64 atomics
    #pragma unroll
    for (int off = 32; off; off >>= 1) {
        a_mxy += __shfl_down(a_mxy, off);
        a_mz  += __shfl_down(a_mz,  off);
        a_pdm += __shfl_down(a_pdm, off);
    }
    if (lane == 0) { red[wv * 3 + 0] = a_mxy; red[wv * 3 + 1] = a_mz; red[wv * 3 + 2] = a_pdm; }
    __syncthreads();
    if (t == 0) {
        double s0 = 0, s1 = 0, s2 = 0;
        for (int k = 0; k < 4; ++k) { s0 += red[k * 3]; s1 += red[k * 3 + 1]; s2 += red[k * 3 + 2]; }
        atomicAdd(&acc[0], s0);
        atomicAdd(&acc[1], s1);
        atomicAdd(&acc[2], s2);
    }
}

// kB: block (b, chunk of 1024). Chunk base = reduce of segsums [0, 32c);
// in-block scan of wrapped diffs from stored phases; masked trapz into
// per-slice num (all b) / mass (b==0). Last-done block finalizes.
__global__ __launch_bounds__(256) void kB(
    const float* __restrict__ phase_g,
    const unsigned long long* __restrict__ mask_g,
    const float* __restrict__ x,
    const double* __restrict__ segsum, const double* __restrict__ acc,
    float* __restrict__ num, float* __restrict__ mass,
    unsigned int* __restrict__ ctrl, float* __restrict__ out)
{
    const int blk = blockIdx.x;
    const int b   = blk >> 4;
    const int c   = blk & 15;
    const int t   = threadIdx.x;
    const int lane = t & 63, wv = t >> 6;

    __shared__ double wsum[4], cbred[4];
    __shared__ double cb_s;
    __shared__ float num_s[SS], mass_s[SS];
    __shared__ int last_s;
    if (t < SS) { num_s[t] = 0.0f; mass_s[t] = 0.0f; }

    const int n = c * 1024 + t * 4;
    const size_t base = (size_t)b * NN + n;
    const float4 ph = *(const float4*)(phase_g + base);
    const float pprev = (n > 0)      ? phase_g[base - 1] : 0.0f;
    const float pnext = (n + 4 < NN) ? phase_g[base + 4] : 0.0f;

    float d0 = (n == 0) ? ph.x : wrapf(ph.x - pprev);
    float d1 = wrapf(ph.y - ph.x);
    float d2 = wrapf(ph.z - ph.y);
    float d3 = wrapf(ph.w - ph.z);
    float d4 = (n + 4 < NN) ? wrapf(pnext - ph.w) : 0.0f;

    double l0 = (double)d0;
    double l1 = l0 + (double)d1;
    double l2 = l1 + (double)d2;
    double l3 = l2 + (double)d3;

    // wave-level inclusive scan of per-thread totals
    double v = l3;
    #pragma unroll
    for (int off = 1; off < 64; off <<= 1) {
        double u = __shfl_up(v, off);
        if (lane >= off) v += u;
    }
    if (lane == 63) wsum[wv] = v;

    // chunk base: reduce segsum[b][0 .. 32c)
    double lv = (t < 32 * c) ? segsum[(size_t)b * NSEG + t] : 0.0;
    #pragma unroll
    for (int off = 32; off; off >>= 1) lv += __shfl_down(lv, off);
    if (lane == 0) cbred[wv] = lv;
    __syncthreads();
    if (t == 0) {
        double s = 0;
        for (int k = 0; k < 4; ++k) { double tmp = wsum[k]; wsum[k] = s; s += tmp; }
        cb_s = cbred[0] + cbred[1] + cbred[2] + cbred[3];
    }
    __syncthreads();
    const double tb = cb_s + wsum[wv] + (v - l3);   // exclusive prefix

    double pus[5];
    pus[0] = tb + l0; pus[1] = tb + l1; pus[2] = tb + l2; pus[3] = tb + l3;
    pus[4] = tb + l3 + (double)d4;

    const float4 x4 = *(const float4*)(x + n);
    float xv[5] = {x4.x, x4.y, x4.z, x4.w, (n + 4 < NN) ? x[n + 4] : 0.0f};
    const ulonglong2 m01 = *(const ulonglong2*)(mask_g + n);
    const ulonglong2 m23 = *(const ulonglong2*)(mask_g + n + 2);
    unsigned long long mk[5] = {m01.x, m01.y, m23.x, m23.y,
                                (n + 4 < NN) ? mask_g[n + 4] : 0ull};

    #pragma unroll
    for (int j = 0; j < 4; ++j) {
        int nn = n + j;
        if (nn >= NN - 1) break;
        unsigned long long pm = mk[j] & mk[j + 1];
        if (!pm) continue;
        float dx = xv[j + 1] - xv[j];
        float avg = (float)(0.5 * (pus[j] + pus[j + 1]));
        while (pm) {
            int s = __ffsll((long long)pm) - 1;
            pm &= pm - 1;
            atomicAdd(&mass_s[s], dx);
            atomicAdd(&num_s[s], avg * dx);
        }
    }
    __syncthreads();
    if (t < SS) {
        if (num_s[t] != 0.0f) atomicAdd(&num[b * SS + t], num_s[t]);
        if (b == 0 && mass_s[t] != 0.0f) atomicAdd(&mass[t], mass_s[t]);
    }

    // ---- completion: last block finalizes ----
    __threadfence();
    if (t == 0) last_s = (atomicAdd(&ctrl[2], 1u) == (unsigned)(BB * NCHUNK - 1));
    __syncthreads();
    if (!last_s) return;
    __threadfence();

    __shared__ float mean_sh[BB * SS];
    __shared__ double redpo[4];
    for (int i = t; i < BB * SS; i += 256) mean_sh[i] = num[i] / mass[i & (SS - 1)];
    __syncthreads();

    double po = 0.0;
    for (int i = t; i < BB * SS; i += 256) {
        int s = i & (SS - 1);
        if (s) {
            float d = mean_sh[i] - mean_sh[i - 1] - 0.5f;   // PHASE_OFFSET
            float tn = tanf(0.5f * d);
            po += (double)tn * (double)tn;
        }
    }
    #pragma unroll
    for (int off = 32; off; off >>= 1) po += __shfl_down(po, off);
    if (lane == 0) redpo[wv] = po;

    double mtot = 0.0;
    if (t < SS) {
        mtot = (double)mass[t];
        #pragma unroll
        for (int off = 32; off; off >>= 1) mtot += __shfl_down(mtot, off);
    }
    __syncthreads();
    if (t == 0) {
        double ext = (double)decf(ctrl[0]) - (double)(-decf(ctrl[1]));
        double potot = redpo[0] + redpo[1] + redpo[2] + redpo[3];
        out[0] = (float)(acc[0] / BB / ext);
        out[1] = (float)(acc[1] / BB / ext);
        out[2] = (float)(acc[2] / mtot / ((double)BB * (double)SS));
        out[3] = (float)(potot / ((double)BB * (double)(SS - 1)));
    }
}

extern "C" void kernel_launch(void* const* d_in, const int* in_sizes, int n_in,
                              void* d_out, int out_size, void* d_ws, size_t ws_size,
                              hipStream_t stream)
{
    const float* z   = (const float*)d_in[0];
    const float* xr  = (const float*)d_in[1];
    const float* xi  = (const float*)d_in[2];
    const float* x   = (const float*)d_in[5];
    const float* tgt = (const float*)d_in[6];

    char* w = (char*)d_ws;
    float* phase_g = (float*)w;                                            // 2 MiB
    unsigned long long* mask_g = (unsigned long long*)(w + (size_t)BB * NN * 4);   // 128 KiB
    double* segsum = (double*)((char*)mask_g + NN * 8);                    // 128 KiB
    double* acc    = (double*)((char*)segsum + (size_t)BB * NSEG * 8);     // 3 f64
    float* num     = (float*)(acc + 3);                                    // BB*SS f32
    float* mass    = num + BB * SS;                                        // SS f32
    unsigned int* ctrl = (unsigned int*)(mass + SS);                       // 3 u32

    // zero the atomic accumulators/control block (acc..ctrl contiguous)
    hipMemsetAsync(acc, 0, 3 * 8 + (size_t)BB * SS * 4 + SS * 4 + 3 * 4, stream);

    hipLaunchKernelGGL(kA, dim3(NSEG), dim3(256), 0, stream,
                       z, xr, xi, x, tgt, phase_g, mask_g, segsum, acc, ctrl);
    hipLaunchKernelGGL(kB, dim3(BB * NCHUNK), dim3(256), 0, stream,
                       phase_g, mask_g, x, segsum, acc, num, mass, ctrl, (float*)d_out);
}

// Round 6
// 57.174 us; speedup vs baseline: 1.3772x; 1.3772x over previous
//
#include <hip/hip_runtime.h>
#include <math.h>

#define BB 32
#define NN 16384
#define SS 64
#define NCHUNK 16       // chunks of 1024 n per batch

__device__ __forceinline__ unsigned int encf(float f) {
    unsigned int u = __float_as_uint(f);
    return (u & 0x80000000u) ? ~u : (u | 0x80000000u);   // order-preserving
}
__device__ __forceinline__ float decf(unsigned int u) {
    unsigned int b = (u & 0x80000000u) ? (u ^ 0x80000000u) : ~u;
    return __uint_as_float(b);
}

// k0: reduce the b=0 plane of target_xy (batch-broadcast input) into
// per-n slice-sum tv[n], mask64[n], popcount pc[n]. Block 0 zeroes all
// atomic accumulators (acc, num, mass, ctrl) — no other k0 block touches
// them, so no race; k1/kT run after k0 completes.
__global__ __launch_bounds__(256) void k0(
    const float* __restrict__ tgt,
    float* __restrict__ tv_g, unsigned long long* __restrict__ mask_g,
    unsigned char* __restrict__ pc_g, double* __restrict__ acc,
    float* __restrict__ num, float* __restrict__ mass,
    unsigned int* __restrict__ ctrl)
{
    const int t = threadIdx.x;
    if (blockIdx.x == 0) {
        if (t < 3 * BB) acc[t] = 0.0;
        for (int i = t; i < BB * SS; i += 256) num[i] = 0.0f;
        if (t < SS) mass[t] = 0.0f;
        if (t < 3)  ctrl[t] = 0u;
    }

    const int wave = t >> 6;
    const int lane = t & 63;
    const int sub  = lane >> 4;   // row within 4-row group
    const int sq   = lane & 15;   // float4 index within row (S=64 -> 16)
    const int r    = blockIdx.x * 16 + wave * 4 + sub;   // 1024 blocks x 16 rows

    const float4* tg4 = (const float4*)tgt;   // b=0 plane
    float4 v = tg4[(size_t)r * 16 + sq];
    float sum = v.x + v.y + v.z + v.w;
    unsigned int b4 = (v.x > 0.001f ? 1u : 0u) | (v.y > 0.001f ? 2u : 0u)
                    | (v.z > 0.001f ? 4u : 0u) | (v.w > 0.001f ? 8u : 0u);
    unsigned long long bits = ((unsigned long long)b4) << (sq * 4);
    #pragma unroll
    for (int off = 1; off < 16; off <<= 1) {
        sum  += __shfl_xor(sum, off);
        bits |= __shfl_xor(bits, off);
    }
    if (sq == 0) {
        tv_g[r]   = sum;
        mask_g[r] = bits;
        pc_g[r]   = (unsigned char)__popcll(bits);
    }
}

// k1: per-(batch, chunk-of-1024) main pass (contiguous coalesced mapping).
// Computes the wrapped phase-diff d[n] directly via atan2(cross, dot) of
// consecutive xy vectors (== wrap(p[n]-p[n-1])), stores d_g for kT's scan,
// accumulates per-batch mxy/mz/pdm integrals and per-chunk diff sums.
// b==0 blocks also reduce posAx min/max into ctrl.
__global__ __launch_bounds__(256) void k1(
    const float* __restrict__ z, const float* __restrict__ xr,
    const float* __restrict__ xi, const float* __restrict__ x,
    const float* __restrict__ tv_g, const unsigned char* __restrict__ pc_g,
    float* __restrict__ d_g, double* __restrict__ acc,
    double* __restrict__ chunksum, unsigned int* __restrict__ ctrl)
{
    __shared__ double red[16];
    __shared__ float redmm[8];

    const int blk  = blockIdx.x;
    const int b    = blk >> 4;            // 16 chunks per batch
    const int c    = blk & 15;
    const int t    = threadIdx.x;
    const int wave = t >> 6;
    const int lane = t & 63;

    const int n = c * 1024 + t * 4;
    const size_t base = (size_t)b * NN + n;
    const float4 zv  = *(const float4*)(z  + base);
    const float4 xrv = *(const float4*)(xr + base);
    const float4 xiv = *(const float4*)(xi + base);
    const float4 tvv = *(const float4*)(tv_g + n);
    const uchar4 pcv = *(const uchar4*)(pc_g + n);
    const float4 x4  = *(const float4*)(x + n);

    float xre[6], xim[6];
    xre[1] = xrv.x; xre[2] = xrv.y; xre[3] = xrv.z; xre[4] = xrv.w;
    xim[1] = xiv.x; xim[2] = xiv.y; xim[3] = xiv.z; xim[4] = xiv.w;
    xre[0] = (n > 0)       ? xr[base - 1] : 1.f;
    xim[0] = (n > 0)       ? xi[base - 1] : 0.f;
    xre[5] = (n + 4 < NN)  ? xr[base + 4] : 1.f;
    xim[5] = (n + 4 < NN)  ? xi[base + 4] : 0.f;

    float xs[6];
    xs[1] = x4.x; xs[2] = x4.y; xs[3] = x4.z; xs[4] = x4.w;
    xs[0] = (n > 0)      ? x[n - 1] : 0.f;
    xs[5] = (n + 4 < NN) ? x[n + 4] : 0.f;

    float ur[6], ui[6], rad[6];
    #pragma unroll
    for (int j = 0; j < 6; ++j) {
        float rv = sqrtf(xre[j] * xre[j] + xim[j] * xim[j]);
        rad[j] = rv;
        float inv = rv > 0.f ? 1.0f / rv : 0.f;
        ur[j] = xre[j] * inv; ui[j] = xim[j] * inv;
    }
    const float zz[4] = {zv.x, zv.y, zv.z, zv.w};
    const float tvs[4] = {tvv.x, tvv.y, tvv.z, tvv.w};
    const int pcs[4] = {pcv.x, pcv.y, pcv.z, pcv.w};

    float4 d4v;
    float* dp = (float*)&d4v;

    double a_mxy = 0.0, a_mz = 0.0, a_pdm = 0.0, a_ds = 0.0;
    #pragma unroll
    for (int j = 0; j < 4; ++j) {
        const int gn = n + j;
        const float tv = tvs[j];

        // wrapped diff: angle(z_n * conj(z_{n-1})) ; seed at n==0 is p[0]
        float cr = xim[j + 1] * xre[j] - xre[j + 1] * xim[j];
        float dt = xre[j + 1] * xre[j] + xim[j + 1] * xim[j];
        float d  = (gn == 0) ? atan2f(xim[1], xre[1]) : atan2f(cr, dt);
        dp[j] = d;
        a_ds += (double)d;

        float dxl = xs[j + 1] - xs[j];
        float dxr = xs[j + 2] - xs[j + 1];
        float sinL = ui[j]     * ur[j + 1] - ur[j]     * ui[j + 1];
        float sinR = ui[j + 2] * ur[j + 1] - ur[j + 2] * ui[j + 1];
        float w, pd;
        if (gn == 0)           { w = 0.5f * dxr; pd =  sinR / dxr; }
        else if (gn == NN - 1) { w = 0.5f * dxl; pd = -sinL / dxl; }
        else {
            w = 0.5f * (dxl + dxr);
            float hs = dxl + dxr;
            float ca = -dxr / (dxl * hs);
            float cc =  dxl / (dxr * hs);
            pd = ca * sinL + cc * sinR;
        }
        float dmx = rad[j + 1] - tv;
        a_mxy += (double)(dmx * dmx) * (double)w;
        float tz = sqrtf(1.0f - tv * tv);
        float dz = zz[j] - tz;
        a_mz  += (double)(dz * dz) * (double)w;
        a_pdm += (double)(pd * pd) * (double)(pcs[j]) * (double)w;
    }
    *(float4*)(d_g + base) = d4v;

    // posAx min/max (only the 16 b==0 blocks; values already in registers)
    if (b == 0) {
        float mx = fmaxf(fmaxf(x4.x, x4.y), fmaxf(x4.z, x4.w));
        float mn = fminf(fminf(x4.x, x4.y), fminf(x4.z, x4.w));
        #pragma unroll
        for (int off = 32; off; off >>= 1) {
            mx = fmaxf(mx, __shfl_down(mx, off));
            mn = fminf(mn, __shfl_down(mn, off));
        }
        if (lane == 0) { redmm[wave] = mx; redmm[4 + wave] = mn; }
    }

    // block reduce 4 doubles
    #pragma unroll
    for (int off = 32; off; off >>= 1) {
        a_mxy += __shfl_down(a_mxy, off);
        a_mz  += __shfl_down(a_mz,  off);
        a_pdm += __shfl_down(a_pdm, off);
        a_ds  += __shfl_down(a_ds,  off);
    }
    if (lane == 0) {
        red[wave * 4 + 0] = a_mxy; red[wave * 4 + 1] = a_mz;
        red[wave * 4 + 2] = a_pdm; red[wave * 4 + 3] = a_ds;
    }
    __syncthreads();
    if (t == 0) {
        double s0 = 0, s1 = 0, s2 = 0, s3 = 0;
        for (int k = 0; k < 4; ++k) {
            s0 += red[k * 4]; s1 += red[k * 4 + 1];
            s2 += red[k * 4 + 2]; s3 += red[k * 4 + 3];
        }
        atomicAdd(&acc[b], s0);
        atomicAdd(&acc[BB + b], s1);
        atomicAdd(&acc[2 * BB + b], s2);
        chunksum[blk] = s3;           // exact chunk total (one block per chunk)
        if (b == 0) {
            float mx = fmaxf(fmaxf(redmm[0], redmm[1]), fmaxf(redmm[2], redmm[3]));
            float mn = fminf(fminf(redmm[4], redmm[5]), fminf(redmm[6], redmm[7]));
            atomicMax(&ctrl[0], encf(mx));
            atomicMax(&ctrl[1], encf(-mn));
        }
    }
}

// kT: per-(batch, chunk) masked trapz of the unwrapped phase, reading the
// stored diffs d_g (no wrap, no phase re-derivation). Chunk base from
// chunksums; in-block f64 scan; per-slice num/mass via LDS f32 atomics.
// Last-finished block finalizes all four losses.
__global__ __launch_bounds__(256) void kT(
    const float* __restrict__ d_g,
    const unsigned long long* __restrict__ mask_g,
    const float* __restrict__ x,
    const double* __restrict__ chunksum, const double* __restrict__ acc,
    float* __restrict__ num, float* __restrict__ mass,
    unsigned int* __restrict__ ctrl, float* __restrict__ out)
{
    const int blk = blockIdx.x;
    const int b   = blk >> 4;
    const int c   = blk & 15;
    const int t   = threadIdx.x;
    const int lane = t & 63, wv = t >> 6;

    __shared__ double wsum[4];
    __shared__ double cb_s;
    __shared__ float num_s[SS], mass_s[SS];
    __shared__ int last_s;
    if (t < SS) { num_s[t] = 0.0f; mass_s[t] = 0.0f; }

    // chunk base: wave 0 lanes 0..14 read earlier chunksums in parallel
    if (wv == 0) {
        double lv = (lane < c) ? chunksum[b * NCHUNK + lane] : 0.0;
        #pragma unroll
        for (int off = 8; off; off >>= 1) lv += __shfl_down(lv, off);
        if (lane == 0) cb_s = lv;
    }

    const int n = c * 1024 + t * 4;
    const size_t base = (size_t)b * NN + n;
    const float4 dv = *(const float4*)(d_g + base);
    const float d4 = (n + 4 < NN) ? d_g[base + 4] : 0.0f;

    double l0 = (double)dv.x;
    double l1 = l0 + (double)dv.y;
    double l2 = l1 + (double)dv.z;
    double l3 = l2 + (double)dv.w;

    // wave-level inclusive scan of per-thread totals
    double v = l3;
    #pragma unroll
    for (int off = 1; off < 64; off <<= 1) {
        double u = __shfl_up(v, off);
        if (lane >= off) v += u;
    }
    if (lane == 63) wsum[wv] = v;
    __syncthreads();
    if (t == 0) {
        double s = 0;
        for (int k = 0; k < 4; ++k) { double tmp = wsum[k]; wsum[k] = s; s += tmp; }
    }
    __syncthreads();
    const double tb = cb_s + wsum[wv] + (v - l3);   // exclusive prefix

    double pus[5];
    pus[0] = tb + l0; pus[1] = tb + l1; pus[2] = tb + l2; pus[3] = tb + l3;
    pus[4] = tb + l3 + (double)d4;

    const float4 x4 = *(const float4*)(x + n);
    float xv[5] = {x4.x, x4.y, x4.z, x4.w, (n + 4 < NN) ? x[n + 4] : 0.0f};
    const ulonglong2 m01 = *(const ulonglong2*)(mask_g + n);
    const ulonglong2 m23 = *(const ulonglong2*)(mask_g + n + 2);
    unsigned long long mk[5] = {m01.x, m01.y, m23.x, m23.y,
                                (n + 4 < NN) ? mask_g[n + 4] : 0ull};

    #pragma unroll
    for (int j = 0; j < 4; ++j) {
        int nn = n + j;
        if (nn >= NN - 1) break;
        unsigned long long pm = mk[j] & mk[j + 1];
        if (!pm) continue;
        float dx = xv[j + 1] - xv[j];
        float avg = (float)(0.5 * (pus[j] + pus[j + 1]));
        while (pm) {
            int s = __ffsll((long long)pm) - 1;
            pm &= pm - 1;
            atomicAdd(&mass_s[s], dx);
            atomicAdd(&num_s[s], avg * dx);
        }
    }
    __syncthreads();
    if (t < SS) {
        if (num_s[t] != 0.0f) atomicAdd(&num[b * SS + t], num_s[t]);
        if (b == 0 && mass_s[t] != 0.0f) atomicAdd(&mass[t], mass_s[t]);
    }

    // ---- completion: last-finished block finalizes ----
    __threadfence();
    if (t == 0) last_s = (atomicAdd(&ctrl[2], 1u) == (unsigned)(BB * NCHUNK - 1));
    __syncthreads();
    if (!last_s) return;
    __threadfence();

    __shared__ float mean_sh[BB * SS];
    __shared__ double redpo[4];
    for (int i = t; i < BB * SS; i += 256) mean_sh[i] = num[i] / mass[i & (SS - 1)];
    __syncthreads();

    double po = 0.0;
    for (int i = t; i < BB * SS; i += 256) {
        int s = i & (SS - 1);
        if (s) {
            float d = mean_sh[i] - mean_sh[i - 1] - 0.5f;   // PHASE_OFFSET
            float tn = tanf(0.5f * d);
            po += (double)tn * (double)tn;
        }
    }
    #pragma unroll
    for (int off = 32; off; off >>= 1) po += __shfl_down(po, off);
    if (lane == 0) redpo[wv] = po;

    double mtot = 0.0;
    if (t < SS) {
        mtot = (double)mass[t];
        #pragma unroll
        for (int off = 32; off; off >>= 1) mtot += __shfl_down(mtot, off);
    }
    __syncthreads();
    if (t == 0) {
        double s0 = 0, s1 = 0, s2 = 0;
        for (int b2 = 0; b2 < BB; ++b2) {
            s0 += acc[b2]; s1 += acc[BB + b2]; s2 += acc[2 * BB + b2];
        }
        double ext = (double)decf(ctrl[0]) - (double)(-decf(ctrl[1]));
        double potot = redpo[0] + redpo[1] + redpo[2] + redpo[3];
        out[0] = (float)(s0 / BB / ext);
        out[1] = (float)(s1 / BB / ext);
        out[2] = (float)(s2 / mtot / ((double)BB * (double)SS));
        out[3] = (float)(potot / ((double)BB * (double)(SS - 1)));
    }
}

extern "C" void kernel_launch(void* const* d_in, const int* in_sizes, int n_in,
                              void* d_out, int out_size, void* d_ws, size_t ws_size,
                              hipStream_t stream)
{
    const float* z   = (const float*)d_in[0];
    const float* xr  = (const float*)d_in[1];
    const float* xi  = (const float*)d_in[2];
    const float* x   = (const float*)d_in[5];
    const float* tgt = (const float*)d_in[6];

    char* w = (char*)d_ws;
    float* d_gw = (float*)w;                                               // 2 MiB
    unsigned long long* mask_g = (unsigned long long*)(w + (size_t)BB * NN * 4);   // 128 KiB
    float* tv_g = (float*)((char*)mask_g + NN * 8);                        // 64 KiB
    unsigned char* pc_g = (unsigned char*)((char*)tv_g + NN * 4);          // 16 KiB
    double* acc      = (double*)((char*)pc_g + NN);                        // 96 f64
    double* chunksum = acc + 3 * BB;                                       // 512 f64
    float* num       = (float*)(chunksum + BB * NCHUNK);                   // 2048 f32
    float* mass      = num + BB * SS;                                      // 64 f32
    unsigned int* ctrl = (unsigned int*)(mass + SS);                       // 3 u32

    hipLaunchKernelGGL(k0, dim3(1024), dim3(256), 0, stream,
                       tgt, tv_g, mask_g, pc_g, acc, num, mass, ctrl);
    hipLaunchKernelGGL(k1, dim3(BB * NCHUNK), dim3(256), 0, stream,
                       z, xr, xi, x, tv_g, pc_g, d_gw, acc, chunksum, ctrl);
    hipLaunchKernelGGL(kT, dim3(BB * NCHUNK), dim3(256), 0, stream,
                       d_gw, mask_g, x, chunksum, acc, num, mass, ctrl, (float*)d_out);
}

// Round 7
// 28.910 us; speedup vs baseline: 2.7236x; 1.9777x over previous
//
#include <hip/hip_runtime.h>
#include <math.h>

#define BB 32
#define NN 16384
#define SS 64
#define NCHUNK 16       // chunks of 1024 n per batch

__device__ __forceinline__ unsigned int encf(float f) {
    unsigned int u = __float_as_uint(f);
    return (u & 0x80000000u) ? ~u : (u | 0x80000000u);   // order-preserving
}
__device__ __forceinline__ float decf(unsigned int u) {
    unsigned int b = (u & 0x80000000u) ? (u ^ 0x80000000u) : ~u;
    return __uint_as_float(b);
}

// k0: reduce the b=0 plane of target_xy (batch-broadcast input) into
// per-n slice-sum tv[n], mask64[n], popcount pc[n]. Block 0 zeroes all
// atomic accumulators (acc, num, mass, ctrl) — replay-safe, race-free.
__global__ __launch_bounds__(256) void k0(
    const float* __restrict__ tgt,
    float* __restrict__ tv_g, unsigned long long* __restrict__ mask_g,
    unsigned char* __restrict__ pc_g, double* __restrict__ acc,
    float* __restrict__ num, float* __restrict__ mass,
    unsigned int* __restrict__ ctrl)
{
    const int t = threadIdx.x;
    if (blockIdx.x == 0) {
        if (t < 3 * BB) acc[t] = 0.0;
        for (int i = t; i < BB * SS; i += 256) num[i] = 0.0f;
        if (t < SS) mass[t] = 0.0f;
        if (t < 2)  ctrl[t] = 0u;
    }

    const int wave = t >> 6;
    const int lane = t & 63;
    const int sub  = lane >> 4;   // row within 4-row group
    const int sq   = lane & 15;   // float4 index within row (S=64 -> 16)
    const int r    = blockIdx.x * 16 + wave * 4 + sub;   // 1024 blocks x 16 rows

    const float4* tg4 = (const float4*)tgt;   // b=0 plane
    float4 v = tg4[(size_t)r * 16 + sq];
    float sum = v.x + v.y + v.z + v.w;
    unsigned int b4 = (v.x > 0.001f ? 1u : 0u) | (v.y > 0.001f ? 2u : 0u)
                    | (v.z > 0.001f ? 4u : 0u) | (v.w > 0.001f ? 8u : 0u);
    unsigned long long bits = ((unsigned long long)b4) << (sq * 4);
    #pragma unroll
    for (int off = 1; off < 16; off <<= 1) {
        sum  += __shfl_xor(sum, off);
        bits |= __shfl_xor(bits, off);
    }
    if (sq == 0) {
        tv_g[r]   = sum;
        mask_g[r] = bits;
        pc_g[r]   = (unsigned char)__popcll(bits);
    }
}

// k1: per-(batch, chunk-of-1024) main pass. Wrapped phase-diff d[n] via
// atan2(cross, dot) — the (1,0) halo at n==0 makes the seed p[0] fall out
// of the same formula, branch-free. Stores d_g; accumulates per-batch
// mxy/mz/pdm and per-chunk diff sums; b==0 blocks reduce posAx extent.
__global__ __launch_bounds__(256) void k1(
    const float* __restrict__ z, const float* __restrict__ xr,
    const float* __restrict__ xi, const float* __restrict__ x,
    const float* __restrict__ tv_g, const unsigned char* __restrict__ pc_g,
    float* __restrict__ d_g, double* __restrict__ acc,
    double* __restrict__ chunksum, unsigned int* __restrict__ ctrl)
{
    __shared__ double red[16];
    __shared__ float redmm[8];

    const int blk  = blockIdx.x;
    const int b    = blk >> 4;            // 16 chunks per batch
    const int c    = blk & 15;
    const int t    = threadIdx.x;
    const int wave = t >> 6;
    const int lane = t & 63;

    const int n = c * 1024 + t * 4;
    const size_t base = (size_t)b * NN + n;
    const float4 zv  = *(const float4*)(z  + base);
    const float4 xrv = *(const float4*)(xr + base);
    const float4 xiv = *(const float4*)(xi + base);
    const float4 tvv = *(const float4*)(tv_g + n);
    const uchar4 pcv = *(const uchar4*)(pc_g + n);
    const float4 x4  = *(const float4*)(x + n);

    float xre[6], xim[6];
    xre[1] = xrv.x; xre[2] = xrv.y; xre[3] = xrv.z; xre[4] = xrv.w;
    xim[1] = xiv.x; xim[2] = xiv.y; xim[3] = xiv.z; xim[4] = xiv.w;
    xre[0] = (n > 0)       ? xr[base - 1] : 1.f;
    xim[0] = (n > 0)       ? xi[base - 1] : 0.f;
    xre[5] = (n + 4 < NN)  ? xr[base + 4] : 1.f;
    xim[5] = (n + 4 < NN)  ? xi[base + 4] : 0.f;

    float xs[6];
    xs[1] = x4.x; xs[2] = x4.y; xs[3] = x4.z; xs[4] = x4.w;
    xs[0] = (n > 0)      ? x[n - 1] : 0.f;
    xs[5] = (n + 4 < NN) ? x[n + 4] : 0.f;

    float ur[6], ui[6], rad[6];
    #pragma unroll
    for (int j = 0; j < 6; ++j) {
        float rv = sqrtf(xre[j] * xre[j] + xim[j] * xim[j]);
        rad[j] = rv;
        float inv = rv > 0.f ? 1.0f / rv : 0.f;
        ur[j] = xre[j] * inv; ui[j] = xim[j] * inv;
    }
    const float zz[4] = {zv.x, zv.y, zv.z, zv.w};
    const float tvs[4] = {tvv.x, tvv.y, tvv.z, tvv.w};
    const int pcs[4] = {pcv.x, pcv.y, pcv.z, pcv.w};

    float4 d4v;
    float* dp = (float*)&d4v;

    double a_mxy = 0.0, a_mz = 0.0, a_pdm = 0.0, a_ds = 0.0;
    #pragma unroll
    for (int j = 0; j < 4; ++j) {
        const int gn = n + j;
        const float tv = tvs[j];

        // wrapped diff: angle(z_n * conj(z_{n-1})); halo (1,0) at n==0
        // makes this exactly atan2(im, re) = p[0], the cumsum seed.
        float cr = xim[j + 1] * xre[j] - xre[j + 1] * xim[j];
        float dt = xre[j + 1] * xre[j] + xim[j + 1] * xim[j];
        float d  = atan2f(cr, dt);
        dp[j] = d;
        a_ds += (double)d;

        float dxl = xs[j + 1] - xs[j];
        float dxr = xs[j + 2] - xs[j + 1];
        float sinL = ui[j]     * ur[j + 1] - ur[j]     * ui[j + 1];
        float sinR = ui[j + 2] * ur[j + 1] - ur[j + 2] * ui[j + 1];
        float w, pd;
        if (gn == 0)           { w = 0.5f * dxr; pd =  sinR / dxr; }
        else if (gn == NN - 1) { w = 0.5f * dxl; pd = -sinL / dxl; }
        else {
            w = 0.5f * (dxl + dxr);
            float hs = dxl + dxr;
            float ca = -dxr / (dxl * hs);
            float cc =  dxl / (dxr * hs);
            pd = ca * sinL + cc * sinR;
        }
        float dmx = rad[j + 1] - tv;
        a_mxy += (double)(dmx * dmx) * (double)w;
        float tz = sqrtf(1.0f - tv * tv);
        float dz = zz[j] - tz;
        a_mz  += (double)(dz * dz) * (double)w;
        a_pdm += (double)(pd * pd) * (double)(pcs[j]) * (double)w;
    }
    *(float4*)(d_g + base) = d4v;

    // posAx min/max (only the 16 b==0 blocks; values already in registers)
    if (b == 0) {
        float mx = fmaxf(fmaxf(x4.x, x4.y), fmaxf(x4.z, x4.w));
        float mn = fminf(fminf(x4.x, x4.y), fminf(x4.z, x4.w));
        #pragma unroll
        for (int off = 32; off; off >>= 1) {
            mx = fmaxf(mx, __shfl_down(mx, off));
            mn = fminf(mn, __shfl_down(mn, off));
        }
        if (lane == 0) { redmm[wave] = mx; redmm[4 + wave] = mn; }
    }

    // block reduce 4 doubles
    #pragma unroll
    for (int off = 32; off; off >>= 1) {
        a_mxy += __shfl_down(a_mxy, off);
        a_mz  += __shfl_down(a_mz,  off);
        a_pdm += __shfl_down(a_pdm, off);
        a_ds  += __shfl_down(a_ds,  off);
    }
    if (lane == 0) {
        red[wave * 4 + 0] = a_mxy; red[wave * 4 + 1] = a_mz;
        red[wave * 4 + 2] = a_pdm; red[wave * 4 + 3] = a_ds;
    }
    __syncthreads();
    if (t == 0) {
        double s0 = 0, s1 = 0, s2 = 0, s3 = 0;
        for (int k = 0; k < 4; ++k) {
            s0 += red[k * 4]; s1 += red[k * 4 + 1];
            s2 += red[k * 4 + 2]; s3 += red[k * 4 + 3];
        }
        atomicAdd(&acc[b], s0);
        atomicAdd(&acc[BB + b], s1);
        atomicAdd(&acc[2 * BB + b], s2);
        chunksum[blk] = s3;           // exact chunk total (one block per chunk)
        if (b == 0) {
            float mx = fmaxf(fmaxf(redmm[0], redmm[1]), fmaxf(redmm[2], redmm[3]));
            float mn = fminf(fminf(redmm[4], redmm[5]), fminf(redmm[6], redmm[7]));
            atomicMax(&ctrl[0], encf(mx));
            atomicMax(&ctrl[1], encf(-mn));
        }
    }
}

// kT: per-(batch, chunk) masked trapz of the unwrapped phase from stored
// diffs. Chunk base from chunksums; in-block f64 scan; per-slice num/mass
// via LDS f32 atomics -> global atomics. NO fences, NO finalize here.
__global__ __launch_bounds__(256) void kT(
    const float* __restrict__ d_g,
    const unsigned long long* __restrict__ mask_g,
    const float* __restrict__ x,
    const double* __restrict__ chunksum,
    float* __restrict__ num, float* __restrict__ mass)
{
    const int blk = blockIdx.x;
    const int b   = blk >> 4;
    const int c   = blk & 15;
    const int t   = threadIdx.x;
    const int lane = t & 63, wv = t >> 6;

    __shared__ double wsum[4];
    __shared__ double cb_s;
    __shared__ float num_s[SS], mass_s[SS];
    if (t < SS) { num_s[t] = 0.0f; mass_s[t] = 0.0f; }

    // chunk base: wave 0 lanes < c read earlier chunksums in parallel
    if (wv == 0) {
        double lv = (lane < c) ? chunksum[b * NCHUNK + lane] : 0.0;
        #pragma unroll
        for (int off = 8; off; off >>= 1) lv += __shfl_down(lv, off);
        if (lane == 0) cb_s = lv;
    }

    const int n = c * 1024 + t * 4;
    const size_t base = (size_t)b * NN + n;
    const float4 dv = *(const float4*)(d_g + base);
    const float d4 = (n + 4 < NN) ? d_g[base + 4] : 0.0f;

    double l0 = (double)dv.x;
    double l1 = l0 + (double)dv.y;
    double l2 = l1 + (double)dv.z;
    double l3 = l2 + (double)dv.w;

    // wave-level inclusive scan of per-thread totals
    double v = l3;
    #pragma unroll
    for (int off = 1; off < 64; off <<= 1) {
        double u = __shfl_up(v, off);
        if (lane >= off) v += u;
    }
    if (lane == 63) wsum[wv] = v;
    __syncthreads();
    if (t == 0) {
        double s = 0;
        for (int k = 0; k < 4; ++k) { double tmp = wsum[k]; wsum[k] = s; s += tmp; }
    }
    __syncthreads();
    const double tb = cb_s + wsum[wv] + (v - l3);   // exclusive prefix

    double pus[5];
    pus[0] = tb + l0; pus[1] = tb + l1; pus[2] = tb + l2; pus[3] = tb + l3;
    pus[4] = tb + l3 + (double)d4;

    const float4 x4 = *(const float4*)(x + n);
    float xv[5] = {x4.x, x4.y, x4.z, x4.w, (n + 4 < NN) ? x[n + 4] : 0.0f};
    const ulonglong2 m01 = *(const ulonglong2*)(mask_g + n);
    const ulonglong2 m23 = *(const ulonglong2*)(mask_g + n + 2);
    unsigned long long mk[5] = {m01.x, m01.y, m23.x, m23.y,
                                (n + 4 < NN) ? mask_g[n + 4] : 0ull};

    #pragma unroll
    for (int j = 0; j < 4; ++j) {
        int nn = n + j;
        if (nn >= NN - 1) break;
        unsigned long long pm = mk[j] & mk[j + 1];
        if (!pm) continue;
        float dx = xv[j + 1] - xv[j];
        float avg = (float)(0.5 * (pus[j] + pus[j + 1]));
        while (pm) {
            int s = __ffsll((long long)pm) - 1;
            pm &= pm - 1;
            atomicAdd(&mass_s[s], dx);
            atomicAdd(&num_s[s], avg * dx);
        }
    }
    __syncthreads();
    if (t < SS) {
        if (num_s[t] != 0.0f) atomicAdd(&num[b * SS + t], num_s[t]);
        if (b == 0 && mass_s[t] != 0.0f) atomicAdd(&mass[t], mass_s[t]);
    }
}

// k4: finalization (1 block; kernel boundary provides coherence)
__global__ __launch_bounds__(256) void k4(
    const double* __restrict__ acc,
    const float* __restrict__ num, const float* __restrict__ mass,
    const unsigned int* __restrict__ ctrl, float* __restrict__ out)
{
    const int t = threadIdx.x;
    const int lane = t & 63, wv = t >> 6;
    __shared__ float mean_sh[BB * SS];
    __shared__ double redpo[4];
    __shared__ double mtot_s;

    for (int i = t; i < BB * SS; i += 256) mean_sh[i] = num[i] / mass[i & (SS - 1)];

    double mtot = 0.0;
    if (t < SS) {
        mtot = (double)mass[t];
        #pragma unroll
        for (int off = 32; off; off >>= 1) mtot += __shfl_down(mtot, off);
        if (t == 0) mtot_s = mtot;
    }
    __syncthreads();

    double po = 0.0;
    for (int i = t; i < BB * SS; i += 256) {
        int s = i & (SS - 1);
        if (s) {
            float d = mean_sh[i] - mean_sh[i - 1] - 0.5f;   // PHASE_OFFSET
            float tn = tanf(0.5f * d);
            po += (double)tn * (double)tn;
        }
    }
    #pragma unroll
    for (int off = 32; off; off >>= 1) po += __shfl_down(po, off);
    if (lane == 0) redpo[wv] = po;
    __syncthreads();

    if (t == 0) {
        double s0 = 0, s1 = 0, s2 = 0;
        for (int b2 = 0; b2 < BB; ++b2) {
            s0 += acc[b2]; s1 += acc[BB + b2]; s2 += acc[2 * BB + b2];
        }
        double ext = (double)decf(ctrl[0]) - (double)(-decf(ctrl[1]));
        double potot = redpo[0] + redpo[1] + redpo[2] + redpo[3];
        out[0] = (float)(s0 / BB / ext);
        out[1] = (float)(s1 / BB / ext);
        out[2] = (float)(s2 / mtot_s / ((double)BB * (double)SS));
        out[3] = (float)(potot / ((double)BB * (double)(SS - 1)));
    }
}

extern "C" void kernel_launch(void* const* d_in, const int* in_sizes, int n_in,
                              void* d_out, int out_size, void* d_ws, size_t ws_size,
                              hipStream_t stream)
{
    const float* z   = (const float*)d_in[0];
    const float* xr  = (const float*)d_in[1];
    const float* xi  = (const float*)d_in[2];
    const float* x   = (const float*)d_in[5];
    const float* tgt = (const float*)d_in[6];

    char* w = (char*)d_ws;
    float* d_gw = (float*)w;                                               // 2 MiB
    unsigned long long* mask_g = (unsigned long long*)(w + (size_t)BB * NN * 4);   // 128 KiB
    float* tv_g = (float*)((char*)mask_g + NN * 8);                        // 64 KiB
    unsigned char* pc_g = (unsigned char*)((char*)tv_g + NN * 4);          // 16 KiB
    double* acc      = (double*)((char*)pc_g + NN);                        // 96 f64
    double* chunksum = acc + 3 * BB;                                       // 512 f64
    float* num       = (float*)(chunksum + BB * NCHUNK);                   // 2048 f32
    float* mass      = num + BB * SS;                                      // 64 f32
    unsigned int* ctrl = (unsigned int*)(mass + SS);                       // 2 u32

    hipLaunchKernelGGL(k0, dim3(1024), dim3(256), 0, stream,
                       tgt, tv_g, mask_g, pc_g, acc, num, mass, ctrl);
    hipLaunchKernelGGL(k1, dim3(BB * NCHUNK), dim3(256), 0, stream,
                       z, xr, xi, x, tv_g, pc_g, d_gw, acc, chunksum, ctrl);
    hipLaunchKernelGGL(kT, dim3(BB * NCHUNK), dim3(256), 0, stream,
                       d_gw, mask_g, x, chunksum, num, mass);
    hipLaunchKernelGGL(k4, dim3(1), dim3(256), 0, stream,
                       acc, num, mass, ctrl, (float*)d_out);
}